// Round 7
// baseline (570.138 us; speedup 1.0000x reference)
//
#include <hip/hip_runtime.h>
#include <math.h>
#include <stdint.h>

#define S 2048
#define HID 2048
#define NH 16
#define QL 1536
#define KVL 512
#define DN 128
#define DR 64
#define DV 128
#define DQ 192
#define IH 4
#define ID 128
#define TOPK 1024

#define N1 2244   // Wq_a(1536) | Wkv_a(576) | IWk(128) | IWproj(4)
#define N2 3584   // Wq_b(3072) | IWq_b(512)

#define CDIV(a,b) (((a)+(b)-1)/(b))

typedef float f32x4 __attribute__((ext_vector_type(4)));
typedef short bf16x8 __attribute__((ext_vector_type(8)));

__device__ __forceinline__ ushort f2b(float f) {
    uint32_t u = __float_as_uint(f);
    u += 0x7fffu + ((u >> 16) & 1u);
    return (ushort)(u >> 16);
}

#define GLL16(g, l)                                                            \
    __builtin_amdgcn_global_load_lds(                                          \
        (const __attribute__((address_space(1))) void*)(g),                    \
        (__attribute__((address_space(3))) void*)(l), 16, 0, 0)

// ============ bf16 MFMA GEMM: C[M,N]f32 = A[M,K] @ BT[N,K] ===================
__global__ __launch_bounds__(256) void gemm_bt(const ushort* __restrict__ A,
                                               const ushort* __restrict__ BT,
                                               float* __restrict__ C,
                                               int M, int N, int K) {
    __shared__ ushort As[128 * 32];
    __shared__ ushort Bs[128 * 32];
    const int tid = threadIdx.x;
    const int w = tid >> 6, l = tid & 63;
    const int quad = l >> 4, lane = l & 15;
    const int row0 = blockIdx.y * 128, col0 = blockIdx.x * 128;
    const int wr = (w >> 1) * 64, wc = (w & 1) * 64;
    f32x4 acc[4][4];
#pragma unroll
    for (int i = 0; i < 4; i++)
#pragma unroll
        for (int j = 0; j < 4; j++) acc[i][j] = (f32x4)0.f;

    const int srow = w * 32 + (l >> 2);
    const int c8 = (l & 3) * 8;
    const ushort* pa0 = A + (size_t)(row0 + srow) * K + c8;
    const ushort* pa1 = A + (size_t)(row0 + srow + 16) * K + c8;
    int bn0 = col0 + srow;      if (bn0 > N - 1) bn0 = N - 1;
    int bn1 = col0 + srow + 16; if (bn1 > N - 1) bn1 = N - 1;
    const ushort* pb0 = BT + (size_t)bn0 * K + c8;
    const ushort* pb1 = BT + (size_t)bn1 * K + c8;
    ushort* sa0 = As + srow * 32 + c8;
    ushort* sa1 = sa0 + 16 * 32;
    ushort* sb0 = Bs + srow * 32 + c8;
    ushort* sb1 = sb0 + 16 * 32;

    for (int k0 = 0; k0 < K; k0 += 32) {
        __syncthreads();
        GLL16(pa0 + k0, sa0);
        GLL16(pa1 + k0, sa1);
        GLL16(pb0 + k0, sb0);
        GLL16(pb1 + k0, sb1);
        __syncthreads();
        bf16x8 af[4], bf[4];
#pragma unroll
        for (int mi = 0; mi < 4; mi++)
            af[mi] = *(const bf16x8*)(As + (wr + mi * 16 + lane) * 32 + quad * 8);
#pragma unroll
        for (int ni = 0; ni < 4; ni++)
            bf[ni] = *(const bf16x8*)(Bs + (wc + ni * 16 + lane) * 32 + quad * 8);
#pragma unroll
        for (int mi = 0; mi < 4; mi++)
#pragma unroll
            for (int ni = 0; ni < 4; ni++)
                acc[mi][ni] = __builtin_amdgcn_mfma_f32_16x16x32_bf16(af[mi], bf[ni], acc[mi][ni], 0, 0, 0);
    }
#pragma unroll
    for (int mi = 0; mi < 4; mi++)
#pragma unroll
        for (int ni = 0; ni < 4; ni++)
#pragma unroll
            for (int r = 0; r < 4; r++) {
                int row = row0 + wr + mi * 16 + quad * 4 + r;
                int col = col0 + wc + ni * 16 + lane;
                if (col < N) C[(size_t)row * N + col] = acc[mi][ni][r];
            }
}

// ============ same GEMM, bf16 output (for kvexp) =============================
__global__ __launch_bounds__(256) void gemm_bt_h(const ushort* __restrict__ A,
                                                 const ushort* __restrict__ BT,
                                                 ushort* __restrict__ C,
                                                 int M, int N, int K) {
    __shared__ ushort As[128 * 32];
    __shared__ ushort Bs[128 * 32];
    const int tid = threadIdx.x;
    const int w = tid >> 6, l = tid & 63;
    const int quad = l >> 4, lane = l & 15;
    const int row0 = blockIdx.y * 128, col0 = blockIdx.x * 128;
    const int wr = (w >> 1) * 64, wc = (w & 1) * 64;
    f32x4 acc[4][4];
#pragma unroll
    for (int i = 0; i < 4; i++)
#pragma unroll
        for (int j = 0; j < 4; j++) acc[i][j] = (f32x4)0.f;

    const int srow = w * 32 + (l >> 2);
    const int c8 = (l & 3) * 8;
    const ushort* pa0 = A + (size_t)(row0 + srow) * K + c8;
    const ushort* pa1 = A + (size_t)(row0 + srow + 16) * K + c8;
    int bn0 = col0 + srow;      if (bn0 > N - 1) bn0 = N - 1;
    int bn1 = col0 + srow + 16; if (bn1 > N - 1) bn1 = N - 1;
    const ushort* pb0 = BT + (size_t)bn0 * K + c8;
    const ushort* pb1 = BT + (size_t)bn1 * K + c8;
    ushort* sa0 = As + srow * 32 + c8;
    ushort* sa1 = sa0 + 16 * 32;
    ushort* sb0 = Bs + srow * 32 + c8;
    ushort* sb1 = sb0 + 16 * 32;

    for (int k0 = 0; k0 < K; k0 += 32) {
        __syncthreads();
        GLL16(pa0 + k0, sa0);
        GLL16(pa1 + k0, sa1);
        GLL16(pb0 + k0, sb0);
        GLL16(pb1 + k0, sb1);
        __syncthreads();
        bf16x8 af[4], bf[4];
#pragma unroll
        for (int mi = 0; mi < 4; mi++)
            af[mi] = *(const bf16x8*)(As + (wr + mi * 16 + lane) * 32 + quad * 8);
#pragma unroll
        for (int ni = 0; ni < 4; ni++)
            bf[ni] = *(const bf16x8*)(Bs + (wc + ni * 16 + lane) * 32 + quad * 8);
#pragma unroll
        for (int mi = 0; mi < 4; mi++)
#pragma unroll
            for (int ni = 0; ni < 4; ni++)
                acc[mi][ni] = __builtin_amdgcn_mfma_f32_16x16x32_bf16(af[mi], bf[ni], acc[mi][ni], 0, 0, 0);
    }
#pragma unroll
    for (int mi = 0; mi < 4; mi++)
#pragma unroll
        for (int ni = 0; ni < 4; ni++)
#pragma unroll
            for (int r = 0; r < 4; r++) {
                int row = row0 + wr + mi * 16 + quad * 4 + r;
                int col = col0 + wc + ni * 16 + lane;
                if (col < N) C[(size_t)row * N + col] = f2b(acc[mi][ni][r]);
            }
}

// ============ generic transpose body =========================================
__device__ __forceinline__ void wtrans_body(const float* W, ushort* WT, int K, int N,
                                            int k0, int n0) {
    __shared__ float t[64][65];
    int rr = threadIdx.x >> 6, cc = threadIdx.x & 63;
#pragma unroll
    for (int p = 0; p < 16; p++) {
        int k = k0 + p * 4 + rr, n = n0 + cc;
        t[p * 4 + rr][cc] = (k < K && n < N) ? W[(size_t)k * N + n] : 0.f;
    }
    __syncthreads();
#pragma unroll
    for (int p = 0; p < 16; p++) {
        int n = n0 + p * 4 + rr, k = k0 + cc;
        if (n < N && k < K) WT[(size_t)n * K + k] = f2b(t[cc][p * 4 + rr]);
    }
}

__global__ __launch_bounds__(256) void wtrans(const float* __restrict__ W, ushort* __restrict__ WT,
                                              int K, int N) {
    wtrans_body(W, WT, K, N, blockIdx.x * 64, blockIdx.y * 64);
}

// merged transposes for the 4 x-side weights (K=2048)
__global__ __launch_bounds__(256) void wtrans_c1(const float* __restrict__ W0, const float* __restrict__ W1,
                                                 const float* __restrict__ W2, const float* __restrict__ W3,
                                                 ushort* __restrict__ WT) {
    int yb = blockIdx.y;
    const float* W; int N; size_t off; int y;
    if (yb < 24)      { W = W0; N = 1536; off = 0;                      y = yb; }
    else if (yb < 33) { W = W1; N = 576;  off = (size_t)1536 * HID;     y = yb - 24; }
    else if (yb < 35) { W = W2; N = 128;  off = (size_t)2112 * HID;     y = yb - 33; }
    else              { W = W3; N = 4;    off = (size_t)2240 * HID;     y = yb - 35; }
    wtrans_body(W, WT + off, HID, N, blockIdx.x * 64, y * 64);
}

// merged transposes for the 2 qr-side weights (K=1536)
__global__ __launch_bounds__(256) void wtrans_c2(const float* __restrict__ W0, const float* __restrict__ W1,
                                                 ushort* __restrict__ WT) {
    int yb = blockIdx.y;
    const float* W; int N; size_t off; int y;
    if (yb < 48) { W = W0; N = 3072; off = 0;                  y = yb; }
    else         { W = W1; N = 512;  off = (size_t)3072 * QL;  y = yb - 48; }
    wtrans_body(W, WT + off, QL, N, blockIdx.x * 64, y * 64);
}

// ============ elementwise f32 -> bf16 (n mult of 1024) =======================
__global__ void cvt_bf16(const float* __restrict__ in, ushort* __restrict__ out) {
    int i = blockIdx.x * 256 + threadIdx.x;
    float4 v = *(const float4*)(in + (size_t)i * 4);
    uint32_t lo = (uint32_t)f2b(v.x) | ((uint32_t)f2b(v.y) << 16);
    uint32_t hi = (uint32_t)f2b(v.z) | ((uint32_t)f2b(v.w) << 16);
    *(uint2*)(out + (size_t)i * 4) = make_uint2(lo, hi);
}

// ============ fused post-C1: rmsnorm(qr), rmsnorm(kv), rope(kpe), LN+rope(ki)+T
__global__ __launch_bounds__(256) void post_c1(const float* __restrict__ C1,
                                               const float* __restrict__ qw,
                                               const float* __restrict__ kvw,
                                               const float* __restrict__ ikg,
                                               const float* __restrict__ ikb,
                                               const float* __restrict__ cosb,
                                               const float* __restrict__ sinb,
                                               ushort* __restrict__ qrb,
                                               ushort* __restrict__ kvnb,
                                               float* __restrict__ kpe,
                                               float* __restrict__ kiT) {
    const int t = blockIdx.x, tid = threadIdx.x;
    const float* row = C1 + (size_t)t * N1;
    __shared__ float red[256];
    __shared__ float kis[128];
    // qr sumsq
    float ss = 0.f;
    for (int i = tid; i < 1536; i += 256) { float v = row[i]; ss += v * v; }
    red[tid] = ss; __syncthreads();
    for (int st = 128; st > 0; st >>= 1) { if (tid < st) red[tid] += red[tid + st]; __syncthreads(); }
    float sq = rsqrtf(red[0] / 1536.f + 1e-6f);
    __syncthreads();
    // kv sumsq
    float s2 = 0.f;
    for (int i = tid; i < 512; i += 256) { float v = row[1536 + i]; s2 += v * v; }
    red[tid] = s2; __syncthreads();
    for (int st = 128; st > 0; st >>= 1) { if (tid < st) red[tid] += red[tid + st]; __syncthreads(); }
    float skv = rsqrtf(red[0] / 512.f + 1e-6f);
    __syncthreads();
    // ki mean / var
    float kv_ = (tid < 128) ? row[2112 + tid] : 0.f;
    red[tid] = kv_; __syncthreads();
    for (int st = 128; st > 0; st >>= 1) { if (tid < st) red[tid] += red[tid + st]; __syncthreads(); }
    float mu = red[0] / 128.f;
    __syncthreads();
    red[tid] = kv_ * kv_; __syncthreads();
    for (int st = 128; st > 0; st >>= 1) { if (tid < st) red[tid] += red[tid + st]; __syncthreads(); }
    float var = red[0] / 128.f - mu * mu;
    // normalized writes
    for (int i = tid; i < 1536; i += 256) qrb[(size_t)t * QL + i] = f2b(row[i] * sq * qw[i]);
    for (int i = tid; i < 512; i += 256)  kvnb[(size_t)t * KVL + i] = f2b(row[1536 + i] * skv * kvw[i]);
    // kpe rope (interleaved)
    if (tid < 32) {
        float c = cosb[t * 32 + tid], s = sinb[t * 32 + tid];
        float xr = row[2048 + 2 * tid], xi = row[2048 + 2 * tid + 1];
        kpe[t * 64 + 2 * tid]     = xr * c - xi * s;
        kpe[t * 64 + 2 * tid + 1] = xr * s + xi * c;
    }
    // ki layernorm
    if (tid < 128) kis[tid] = (kv_ - mu) * rsqrtf(var + 1e-6f) * ikg[tid] + ikb[tid];
    __syncthreads();
    // ki rope (non-interleaved, first 64) + transposed store
    if (tid < 128) {
        float outv;
        if (tid < 32) {
            float c = cosb[t * 32 + tid], s = sinb[t * 32 + tid];
            outv = kis[tid] * c - kis[tid + 32] * s;
        } else if (tid < 64) {
            int j = tid - 32;
            float c = cosb[t * 32 + j], s = sinb[t * 32 + j];
            outv = kis[j] * s + kis[tid] * c;
        } else {
            outv = kis[tid];
        }
        kiT[(size_t)tid * S + t] = outv;
    }
}

// ============ fused post-C2: q rope+scale -> qb, qi rope in place ============
__global__ __launch_bounds__(256) void post_c2(float* __restrict__ C2,
                                               const float* __restrict__ cosb,
                                               const float* __restrict__ sinb,
                                               ushort* __restrict__ qb) {
    const int t = blockIdx.x, tid = threadIdx.x;
    __shared__ float cs[32], sn[32];
    if (tid < 32) { cs[tid] = cosb[t * 32 + tid]; sn[tid] = sinb[t * 32 + tid]; }
    __syncthreads();
    const float sc = 0.10412775370051047f;  // 192^-0.5 * log2(e) (exp2-domain softmax)
    const float* src0 = C2 + (size_t)t * N2;
    for (int i = tid; i < NH * 96; i += 256) {
        int h = i / 96, p = i % 96;
        const float* src = src0 + h * 192;
        ushort* dst = qb + ((size_t)h * S + t) * 192;
        if (p < 64) {
            dst[2 * p]     = f2b(src[2 * p] * sc);
            dst[2 * p + 1] = f2b(src[2 * p + 1] * sc);
        } else {
            int j = p - 64;
            float c = cs[j], s = sn[j];
            float xr = src[128 + 2 * j], xi = src[128 + 2 * j + 1];
            dst[128 + 2 * j]     = f2b((xr * c - xi * s) * sc);
            dst[128 + 2 * j + 1] = f2b((xr * s + xi * c) * sc);
        }
    }
    if (tid < 128) {
        int h = tid >> 5, j = tid & 31;
        float* p = C2 + (size_t)t * N2 + 3072 + h * 128;
        float c = cs[j], s = sn[j];
        float x1 = p[j], x2 = p[j + 32];
        p[j] = x1 * c - x2 * s;
        p[j + 32] = x1 * s + x2 * c;
    }
}

// ============ pack kvexp_h + kpe -> kb[NH][S][192], vT[NH][128][S] ===========
__global__ __launch_bounds__(256) void pack_kv(const ushort* __restrict__ kvexp_h,
                                               const float* __restrict__ kpe,
                                               ushort* __restrict__ kb,
                                               ushort* __restrict__ vT) {
    __shared__ ushort t[64][136];
    const int s0 = blockIdx.x * 64, h = blockIdx.y, tid = threadIdx.x;
    const int row = tid >> 2, c = tid & 3;
    const ushort* src = kvexp_h + (size_t)(s0 + row) * 4096 + h * 256;
    ushort* kbr = kb + ((size_t)h * S + s0 + row) * 192;
#pragma unroll
    for (int i = 0; i < 4; i++) {
        int off = c * 32 + i * 8;
        *(uint4*)(kbr + off) = *(const uint4*)(src + off);
        *(uint4*)(&t[row][off]) = *(const uint4*)(src + 128 + off);
    }
    const float* kp = kpe + (size_t)(s0 + row) * 64 + c * 16;
#pragma unroll
    for (int i = 0; i < 16; i++) kbr[128 + c * 16 + i] = f2b(kp[i]);
    __syncthreads();
    const int d = tid >> 1, sh = (tid & 1) * 32;
    ushort* dst = vT + ((size_t)h * 128 + d) * S + s0 + sh;
#pragma unroll
    for (int i = 0; i < 32; i++) dst[i] = t[sh + i][d];
}

// ============ indexer score (fp32, 4 cols/thread, causal region only) ========
__global__ __launch_bounds__(256) void iscore4(const float* __restrict__ qi,
                                               const float* __restrict__ kiT,
                                               const float* __restrict__ iw,
                                               float* __restrict__ iscore) {
    int t = blockIdx.x;
    int s0 = blockIdx.y * 1024;
    if (s0 > t) return;
    int s = s0 + threadIdx.x * 4;
    __shared__ float qs[4 * ID];
    __shared__ float ws4[4];
    for (int i = threadIdx.x; i < 4 * ID; i += 256) qs[i] = qi[(size_t)t * N2 + i];
    if (threadIdx.x < 4) ws4[threadIdx.x] = iw[(size_t)t * N1 + threadIdx.x] * 0.04419417382415922f;
    __syncthreads();
    if (s > t) return;
    float a[4][4];
#pragma unroll
    for (int h = 0; h < 4; h++)
#pragma unroll
        for (int c = 0; c < 4; c++) a[h][c] = 0.f;
    for (int d = 0; d < ID; d++) {
        float4 kv = *(const float4*)(kiT + (size_t)d * S + s);
#pragma unroll
        for (int h = 0; h < 4; h++) {
            float qv = qs[h * ID + d];
            a[h][0] += qv * kv.x; a[h][1] += qv * kv.y;
            a[h][2] += qv * kv.z; a[h][3] += qv * kv.w;
        }
    }
#pragma unroll
    for (int c = 0; c < 4; c++) {
        if (s + c > t) break;
        float sc = fmaxf(a[0][c], 0.f) * ws4[0] + fmaxf(a[1][c], 0.f) * ws4[1] +
                   fmaxf(a[2][c], 0.f) * ws4[2] + fmaxf(a[3][c], 0.f) * ws4[3];
        iscore[(size_t)t * S + s + c] = sc;
    }
}

// ============ exact top-k -> bitmask (registers-resident radix select) =======
__device__ inline unsigned sortable_u32(float f) {
    unsigned u = __float_as_uint(f);
    return (u & 0x80000000u) ? ~u : (u | 0x80000000u);
}

__global__ __launch_bounds__(256) void topk_mask(const float* __restrict__ iscore,
                                                 uint32_t* __restrict__ msk) {
    int t = blockIdx.x, tid = threadIdx.x;
    uint32_t* mrow = msk + (size_t)t * 64;
    if (t < TOPK) {
        if (tid < 64) {
            int full = (t + 1) >> 5;
            uint32_t wv2 = (tid < full) ? 0xFFFFFFFFu : 0u;
            if (tid == full) { int rem = (t + 1) & 31; wv2 = rem ? ((1u << rem) - 1u) : 0u; }
            mrow[tid] = wv2;
        }
        return;
    }
    const float* row = iscore + (size_t)t * S;
    const int n = t + 1;
    const int wv = tid >> 6;
    __shared__ int hist[4][256];
    __shared__ int scan[256];
    __shared__ int bsel, ksel;
    __shared__ uint32_t bytes[256];

    int jb = tid * 8;
    float4 v0 = *(const float4*)(row + jb);
    float4 v1 = *(const float4*)(row + jb + 4);
    uint32_t lsu[8];
    {
        float vvv[8] = {v0.x, v0.y, v0.z, v0.w, v1.x, v1.y, v1.z, v1.w};
#pragma unroll
        for (int i = 0; i < 8; i++)
            lsu[i] = (jb + i < n) ? sortable_u32(vvv[i]) : 0u;
    }
    unsigned prefix = 0, prefmask = 0;
    int k = TOPK;
    for (int pass = 0; pass < 4; pass++) {
        int shift = 24 - pass * 8;
#pragma unroll
        for (int r = 0; r < 4; r++) hist[r][tid] = 0;
        __syncthreads();
#pragma unroll
        for (int i = 0; i < 8; i++) {
            uint32_t u = lsu[i];
            if ((u & prefmask) == prefix) atomicAdd(&hist[wv][(u >> shift) & 255], 1);
        }
        __syncthreads();
        int h = hist[0][tid] + hist[1][tid] + hist[2][tid] + hist[3][tid];
        scan[tid] = h; __syncthreads();
        for (int st = 1; st < 256; st <<= 1) {
            int a = scan[tid];
            int b = (tid + st < 256) ? scan[tid + st] : 0;
            __syncthreads();
            scan[tid] = a + b;
            __syncthreads();
        }
        int snext = (tid < 255) ? scan[tid + 1] : 0;
        if (scan[tid] >= k && snext < k) { bsel = tid; ksel = k - snext; }
        __syncthreads();
        prefix |= ((unsigned)bsel) << shift;
        prefmask |= 0xFFu << shift;
        k = ksel;
        __syncthreads();
    }
    const unsigned u_thr = prefix;
    const int need = k;
    uint32_t gtbits = 0, eqbits = 0;
    int eqcnt = 0;
#pragma unroll
    for (int i = 0; i < 8; i++) {
        uint32_t u = lsu[i];
        if (u > u_thr) gtbits |= 1u << i;
        else if (u == u_thr) { eqbits |= 1u << i; eqcnt++; }
    }
    scan[tid] = eqcnt; __syncthreads();
    for (int st = 1; st < 256; st <<= 1) {
        int a = scan[tid];
        int b = (tid >= st) ? scan[tid - st] : 0;
        __syncthreads();
        scan[tid] = a + b;
        __syncthreads();
    }
    int room = need - (scan[tid] - eqcnt);
    uint32_t keep = 0;
#pragma unroll
    for (int i = 0; i < 8; i++)
        if ((eqbits >> i) & 1u) { if (room > 0) { keep |= 1u << i; room--; } }
    bytes[tid] = gtbits | keep;
    __syncthreads();
    if (tid < 64)
        mrow[tid] = bytes[tid * 4] | (bytes[tid * 4 + 1] << 8) |
                    (bytes[tid * 4 + 2] << 16) | (bytes[tid * 4 + 3] << 24);
}

// ============ split-K flash attention v5 =====================================
// 768 blocks: r8=b&7, j=b>>3; h=r8+8*(j&1) (XCD affinity); idx=j>>1;
// pair=idx&15, part=idx>>4 (3 parts x 11 visits). Chunked LDS layouts:
// chunk(pos)=16B; K pos=(ks*4+kq)*64+quad*16+r15; V pos=(k2*8+nt)*4*16... so
// frag reads are base+lane15*16B (2-way free). exp2-domain softmax (scale
// pre-multiplied by log2e in qb).
__global__ __launch_bounds__(256, 3) void fattn5(const ushort* __restrict__ qb,
                                                 const ushort* __restrict__ kb,
                                                 const ushort* __restrict__ vT,
                                                 const uint32_t* __restrict__ msk,
                                                 float* __restrict__ Opart,
                                                 float* __restrict__ mlbuf) {
    __shared__ ushort Ks[24 * 512];   // 24 KB
    __shared__ ushort Vs[16 * 512];   // 16 KB
    __shared__ ushort Pm[4][16 * 72]; // 9 KB
    const int tid = threadIdx.x;
    const int w = tid >> 6, l = tid & 63, quad = l >> 4, lane = l & 15;
    const int b = blockIdx.x;
    const int r8 = b & 7, j = b >> 3;
    const int h = r8 + 8 * (j & 1);
    const int idx = j >> 1;
    const int pair = idx & 15, part = idx >> 4;
    const int ta = pair, tb = 31 - pair, nA = ta + 1;
    const int vlo = part * 11, vhi = vlo + 11;
    const int qa0 = ta * 64, qb0 = tb * 64;

    bf16x8 qfa[6], qfb[6];
    {
        const ushort* qpa = qb + ((size_t)h * S + qa0 + w * 16 + lane) * 192;
        const ushort* qpb = qb + ((size_t)h * S + qb0 + w * 16 + lane) * 192;
#pragma unroll
        for (int ks = 0; ks < 6; ks++) {
            qfa[ks] = *(const bf16x8*)(qpa + ks * 32 + quad * 8);
            qfb[ks] = *(const bf16x8*)(qpb + ks * 32 + quad * 8);
        }
    }
    f32x4 oa[8], ob[8];
#pragma unroll
    for (int i = 0; i < 8; i++) { oa[i] = (f32x4)0.f; ob[i] = (f32x4)0.f; }
    float ma[4], la[4], mb[4], lb[4];
#pragma unroll
    for (int r = 0; r < 4; r++) { ma[r] = -1e30f; la[r] = 0.f; mb[r] = -1e30f; lb[r] = 0.f; }

    ushort* pw = &Pm[w][0];
    const ushort* kbase = kb + (size_t)h * S * 192;
    const ushort* vbase = vT + (size_t)h * 128 * S;

    for (int kt = 0; kt <= tb; kt++) {
        const int idxB = (kt <= ta) ? 2 * kt : kt + nA;
        const int hasA = (kt <= ta);
        const int idxA = 2 * kt + 1;
        const bool doB = (idxB >= vlo && idxB < vhi);
        const bool doA = hasA && (idxA >= vlo && idxA < vhi);
        if (!(doA || doB)) continue;           // block-uniform
        const int s0 = kt * 64;
        __syncthreads();
        // ---- DMA K: 24 issues (6/wave). issue i: ks=i>>2, kq=i&3; lane: quad,r15
#pragma unroll
        for (int ii = 0; ii < 6; ii++) {
            const int i = w * 6 + ii;
            const int ks = i >> 2, kq = i & 3;
            const ushort* src = kbase + (size_t)(s0 + kq * 16 + lane) * 192 + ks * 32 + quad * 8;
            GLL16(src, Ks + i * 512 + l * 8);
        }
        // ---- DMA V: 16 issues (4/wave). issue i: k2=i>>3, nt=i&7; lane: quad,d15
#pragma unroll
        for (int ii = 0; ii < 4; ii++) {
            const int i = w * 4 + ii;
            const int k2 = i >> 3, nt = i & 7;
            const ushort* src = vbase + (size_t)(nt * 16 + lane) * S + s0 + k2 * 32 + quad * 8;
            GLL16(src, Vs + i * 512 + l * 8);
        }
        __syncthreads();   // drains DMA

#pragma unroll
        for (int pass = 0; pass < 2; pass++) {
            if (pass == 0 && !doA) continue;
            if (pass == 1 && !doB) continue;
            const bf16x8* qf = (pass == 0) ? qfa : qfb;
            f32x4* oacc      = (pass == 0) ? oa : ob;
            float* mm        = (pass == 0) ? ma : mb;
            float* ll        = (pass == 0) ? la : lb;
            const int q0t    = (pass == 0) ? qa0 : qb0;

            // QK^T (scores in log2e domain)
            f32x4 sc[4];
#pragma unroll
            for (int kq = 0; kq < 4; kq++) {
                sc[kq] = (f32x4)0.f;
#pragma unroll
                for (int ks = 0; ks < 6; ks++) {
                    bf16x8 bfr = *(const bf16x8*)(Ks + (ks * 4 + kq) * 512 + quad * 128 + lane * 8);
                    sc[kq] = __builtin_amdgcn_mfma_f32_16x16x32_bf16(qf[ks], bfr, sc[kq], 0, 0, 0);
                }
            }
            // mask words
            uint32_t w0[4], w1[4];
            {
                const int rowbase = q0t + w * 16 + quad * 4;
#pragma unroll
                for (int r = 0; r < 4; r++) {
                    const uint32_t* mp = msk + (size_t)(rowbase + r) * 64 + (s0 >> 5);
                    w0[r] = mp[0]; w1[r] = mp[1];
                }
            }
            float vmax[4] = {-1e30f, -1e30f, -1e30f, -1e30f};
#pragma unroll
            for (int kq = 0; kq < 4; kq++) {
                const int sh = (kq & 1) * 16 + lane;
#pragma unroll
                for (int r = 0; r < 4; r++) {
                    uint32_t word = (kq < 2) ? w0[r] : w1[r];
                    float v = ((word >> sh) & 1u) ? sc[kq][r] : -1e30f;
                    sc[kq][r] = v;
                    vmax[r] = fmaxf(vmax[r], v);
                }
            }
#pragma unroll
            for (int off = 1; off < 16; off <<= 1)
#pragma unroll
                for (int r = 0; r < 4; r++)
                    vmax[r] = fmaxf(vmax[r], __shfl_xor(vmax[r], off, 64));
            float alpha[4], psum[4];
#pragma unroll
            for (int r = 0; r < 4; r++) {
                float mnew = fmaxf(mm[r], vmax[r]);
                alpha[r] = exp2f(mm[r] - mnew);
                mm[r] = mnew;
                psum[r] = 0.f;
            }
#pragma unroll
            for (int kq = 0; kq < 4; kq++)
#pragma unroll
                for (int r = 0; r < 4; r++) {
                    float v = sc[kq][r];
                    float e = (v < -1e29f) ? 0.f : exp2f(v - mm[r]);
                    psum[r] += e;
                    pw[(quad * 4 + r) * 72 + kq * 16 + lane] = f2b(e);
                }
#pragma unroll
            for (int off = 1; off < 16; off <<= 1)
#pragma unroll
                for (int r = 0; r < 4; r++)
                    psum[r] += __shfl_xor(psum[r], off, 64);
#pragma unroll
            for (int r = 0; r < 4; r++) ll[r] = ll[r] * alpha[r] + psum[r];

            bf16x8 pfr[2];
#pragma unroll
            for (int k2 = 0; k2 < 2; k2++)
                pfr[k2] = *(const bf16x8*)(pw + lane * 72 + k2 * 32 + quad * 8);
#pragma unroll
            for (int nt = 0; nt < 8; nt++) {
#pragma unroll
                for (int r = 0; r < 4; r++) oacc[nt][r] *= alpha[r];
#pragma unroll
                for (int k2 = 0; k2 < 2; k2++) {
                    bf16x8 vfr = *(const bf16x8*)(Vs + ((k2 * 8 + nt) * 4 + quad) * 128 + lane * 8);
                    oacc[nt] = __builtin_amdgcn_mfma_f32_16x16x32_bf16(pfr[k2], vfr, oacc[nt], 0, 0, 0);
                }
            }
        }
    }
    // epilogue: f32 partials (unnormalized O + m,l), 3 parts
#pragma unroll
    for (int pass = 0; pass < 2; pass++) {
        const f32x4* oacc = (pass == 0) ? oa : ob;
        const float* mm   = (pass == 0) ? ma : mb;
        const float* ll   = (pass == 0) ? la : lb;
        const int qt      = (pass == 0) ? ta : tb;
        float* Op = Opart + (size_t)((qt * 16 + h) * 3 + part) * (64 * 128);
        float* mlp = mlbuf + (size_t)((qt * 16 + h) * 3 + part) * 128;
#pragma unroll
        for (int nt = 0; nt < 8; nt++)
#pragma unroll
            for (int r = 0; r < 4; r++)
                Op[(w * 16 + quad * 4 + r) * 128 + nt * 16 + lane] = oacc[nt][r];
        if (lane == 0) {
#pragma unroll
            for (int r = 0; r < 4; r++) {
                mlp[(w * 16 + quad * 4 + r) * 2 + 0] = mm[r];
                mlp[(w * 16 + quad * 4 + r) * 2 + 1] = ll[r];
            }
        }
    }
}

// ============ combine 3 split-K partials -> attn_b bf16 ======================
__global__ __launch_bounds__(256) void attn_combine(const float* __restrict__ Opart,
                                                    const float* __restrict__ mlbuf,
                                                    ushort* __restrict__ attn_b) {
    const int qt = blockIdx.x, h = blockIdx.y, tid = threadIdx.x;
    const size_t base = ((size_t)qt * 16 + h) * 3;
    const float* Op0 = Opart + base * 8192;
    const float* Op1 = Op0 + 8192;
    const float* Op2 = Op1 + 8192;
    const float* ml0 = mlbuf + base * 128;
    const float* ml1 = ml0 + 128;
    const float* ml2 = ml1 + 128;
#pragma unroll
    for (int i = 0; i < 32; i++) {
        int id = tid + i * 256;
        int row = id >> 7, d = id & 127;
        float m0 = ml0[row * 2], l0 = ml0[row * 2 + 1];
        float m1 = ml1[row * 2], l1 = ml1[row * 2 + 1];
        float m2 = ml2[row * 2], l2 = ml2[row * 2 + 1];
        float m = fmaxf(fmaxf(m0, m1), m2);
        float e0 = exp2f(m0 - m), e1 = exp2f(m1 - m), e2 = exp2f(m2 - m);
        float linv = 1.f / (l0 * e0 + l1 * e1 + l2 * e2);
        float v = (Op0[id] * e0 + Op1[id] * e1 + Op2[id] * e2) * linv;
        attn_b[(size_t)(qt * 64 + row) * 2048 + h * 128 + d] = f2b(v);
    }
}

// ============ host ===========================================================
extern "C" void kernel_launch(void* const* d_in, const int* in_sizes, int n_in,
                              void* d_out, int out_size, void* d_ws, size_t ws_size,
                              hipStream_t stream) {
    const float* x        = (const float*)d_in[0];
    const float* cosb     = (const float*)d_in[1];
    const float* sinb     = (const float*)d_in[2];
    const float* Wq_a     = (const float*)d_in[4];
    const float* q_norm_w = (const float*)d_in[5];
    const float* Wq_b     = (const float*)d_in[6];
    const float* Wkv_a    = (const float*)d_in[7];
    const float* kv_norm_w= (const float*)d_in[8];
    const float* Wkv_b    = (const float*)d_in[9];
    const float* Wo       = (const float*)d_in[10];
    const float* IWq_b    = (const float*)d_in[11];
    const float* IWk      = (const float*)d_in[12];
    const float* Ik_norm_w= (const float*)d_in[13];
    const float* Ik_norm_b= (const float*)d_in[14];
    const float* IWproj   = (const float*)d_in[15];
    float* out = (float*)d_out;

    char* ws = (char*)d_ws;
    size_t o = 0;
    auto take = [&](size_t b) { char* p = ws + o; o += (b + 255) & ~(size_t)255; return p; };
    ushort* xb     = (ushort*)take((size_t)S * HID * 2);
    ushort* qrb    = (ushort*)take((size_t)S * QL * 2);
    ushort* qb     = (ushort*)take((size_t)NH * S * DQ * 2);
    ushort* kvnb   = (ushort*)take((size_t)S * KVL * 2);
    float*  kpe    = (float*)take((size_t)S * DR * 4);
    ushort* kb     = (ushort*)take((size_t)NH * S * DQ * 2);
    ushort* vT     = (ushort*)take((size_t)NH * DV * S * 2);
    uint32_t* msk  = (uint32_t*)take((size_t)S * 64 * 4);
    float*  mlbuf  = (float*)take((size_t)32 * 16 * 3 * 64 * 2 * 4);
    ushort* WTp    = (ushort*)take((size_t)N2 * QL * 2);            // reused serially
    float*  C1     = (float*)take((size_t)S * N1 * 4);
    char*   big    = take((size_t)32 * 16 * 3 * 8192 * 4 + 1024);   // C2 f32 then Opart
    ushort* kvexp_h= (ushort*)take((size_t)S * 4096 * 2);
    float*  kiT    = (float*)take((size_t)128 * S * 4);
    char*   poolb  = take((size_t)16777216);                        // iscore / attn_b

    float* C2     = (float*)big;              // [S][N2] (qi consumed by iscore)
    float* Opart  = (float*)big;              // [32][16][3][64][128] f32
    float* iscore = (float*)poolb;
    ushort* attn_b = (ushort*)poolb;          // after topk consumed iscore

    // --- x -> bf16
    cvt_bf16<<<(S * HID) / 1024, 256, 0, stream>>>(x, xb);

    // --- concatenated x-GEMM + fused post-processing
    wtrans_c1<<<dim3(32, 36), 256, 0, stream>>>(Wq_a, Wkv_a, IWk, IWproj, WTp);
    gemm_bt<<<dim3(CDIV(N1, 128), S / 128), 256, 0, stream>>>(xb, WTp, C1, S, N1, HID);
    post_c1<<<S, 256, 0, stream>>>(C1, q_norm_w, kv_norm_w, Ik_norm_w, Ik_norm_b,
                                   cosb, sinb, qrb, kvnb, kpe, kiT);

    // --- concatenated qr-GEMM + fused rope
    wtrans_c2<<<dim3(24, 56), 256, 0, stream>>>(Wq_b, IWq_b, WTp);
    gemm_bt<<<dim3(N2 / 128, S / 128), 256, 0, stream>>>(qrb, WTp, C2, S, N2, QL);
    post_c2<<<S, 256, 0, stream>>>(C2, cosb, sinb, qb);

    // --- kv_exp (bf16 out) ; pack kb / vT
    wtrans<<<dim3(8, 64), 256, 0, stream>>>(Wkv_b, WTp, KVL, NH * (DN + DV));
    gemm_bt_h<<<dim3(32, S / 128), 256, 0, stream>>>(kvnb, WTp, kvexp_h, S, NH * (DN + DV), KVL);
    pack_kv<<<dim3(S / 64, NH), 256, 0, stream>>>(kvexp_h, kpe, kb, vT);

    // --- indexer scores + exact top-k -> bitmap
    iscore4<<<dim3(S, S / 1024), 256, 0, stream>>>(C2 + 3072, kiT, C1 + 2240, iscore);
    topk_mask<<<S, 256, 0, stream>>>(iscore, msk);

    // --- split-K masked flash attention (3 parts) + combine
    fattn5<<<768, 256, 0, stream>>>(qb, kb, vT, msk, Opart, mlbuf);
    attn_combine<<<dim3(32, 16), 256, 0, stream>>>(Opart, mlbuf, attn_b);

    // --- out = attn @ Wo
    wtrans<<<dim3(32, 32), 256, 0, stream>>>(Wo, WTp, NH * DV, HID);
    gemm_bt<<<dim3(HID / 128, S / 128), 256, 0, stream>>>(attn_b, WTp, out, S, HID, NH * DV);

    (void)in_sizes; (void)n_in; (void)out_size; (void)ws_size; (void)o;
}

// Round 8
// 539.672 us; speedup vs baseline: 1.0565x; 1.0565x over previous
//
#include <hip/hip_runtime.h>
#include <math.h>
#include <stdint.h>

#define S 2048
#define HID 2048
#define NH 16
#define QL 1536
#define KVL 512
#define DN 128
#define DR 64
#define DV 128
#define DQ 192
#define IH 4
#define ID 128
#define TOPK 1024

#define N1 2244   // Wq_a(1536) | Wkv_a(576) | IWk(128) | IWproj(4)
#define N2 3584   // Wq_b(3072) | IWq_b(512)

#define CDIV(a,b) (((a)+(b)-1)/(b))

typedef float f32x4 __attribute__((ext_vector_type(4)));
typedef short bf16x8 __attribute__((ext_vector_type(8)));

__device__ __forceinline__ ushort f2b(float f) {
    uint32_t u = __float_as_uint(f);
    u += 0x7fffu + ((u >> 16) & 1u);
    return (ushort)(u >> 16);
}

#define GLL16(g, l)                                                            \
    __builtin_amdgcn_global_load_lds(                                          \
        (const __attribute__((address_space(1))) void*)(g),                    \
        (__attribute__((address_space(3))) void*)(l), 16, 0, 0)

// ============ bf16 MFMA GEMM: C[M,N]f32 = A[M,K] @ BT[N,K] ===================
__global__ __launch_bounds__(256) void gemm_bt(const ushort* __restrict__ A,
                                               const ushort* __restrict__ BT,
                                               float* __restrict__ C,
                                               int M, int N, int K) {
    __shared__ ushort As[128 * 32];
    __shared__ ushort Bs[128 * 32];
    const int tid = threadIdx.x;
    const int w = tid >> 6, l = tid & 63;
    const int quad = l >> 4, lane = l & 15;
    const int row0 = blockIdx.y * 128, col0 = blockIdx.x * 128;
    const int wr = (w >> 1) * 64, wc = (w & 1) * 64;
    f32x4 acc[4][4];
#pragma unroll
    for (int i = 0; i < 4; i++)
#pragma unroll
        for (int j = 0; j < 4; j++) acc[i][j] = (f32x4)0.f;

    const int srow = w * 32 + (l >> 2);
    const int c8 = (l & 3) * 8;
    const ushort* pa0 = A + (size_t)(row0 + srow) * K + c8;
    const ushort* pa1 = A + (size_t)(row0 + srow + 16) * K + c8;
    int bn0 = col0 + srow;      if (bn0 > N - 1) bn0 = N - 1;
    int bn1 = col0 + srow + 16; if (bn1 > N - 1) bn1 = N - 1;
    const ushort* pb0 = BT + (size_t)bn0 * K + c8;
    const ushort* pb1 = BT + (size_t)bn1 * K + c8;
    ushort* sa0 = As + srow * 32 + c8;
    ushort* sa1 = sa0 + 16 * 32;
    ushort* sb0 = Bs + srow * 32 + c8;
    ushort* sb1 = sb0 + 16 * 32;

    for (int k0 = 0; k0 < K; k0 += 32) {
        __syncthreads();
        GLL16(pa0 + k0, sa0);
        GLL16(pa1 + k0, sa1);
        GLL16(pb0 + k0, sb0);
        GLL16(pb1 + k0, sb1);
        __syncthreads();
        bf16x8 af[4], bf[4];
#pragma unroll
        for (int mi = 0; mi < 4; mi++)
            af[mi] = *(const bf16x8*)(As + (wr + mi * 16 + lane) * 32 + quad * 8);
#pragma unroll
        for (int ni = 0; ni < 4; ni++)
            bf[ni] = *(const bf16x8*)(Bs + (wc + ni * 16 + lane) * 32 + quad * 8);
#pragma unroll
        for (int mi = 0; mi < 4; mi++)
#pragma unroll
            for (int ni = 0; ni < 4; ni++)
                acc[mi][ni] = __builtin_amdgcn_mfma_f32_16x16x32_bf16(af[mi], bf[ni], acc[mi][ni], 0, 0, 0);
    }
#pragma unroll
    for (int mi = 0; mi < 4; mi++)
#pragma unroll
        for (int ni = 0; ni < 4; ni++)
#pragma unroll
            for (int r = 0; r < 4; r++) {
                int row = row0 + wr + mi * 16 + quad * 4 + r;
                int col = col0 + wc + ni * 16 + lane;
                if (col < N) C[(size_t)row * N + col] = acc[mi][ni][r];
            }
}

// ============ same GEMM, bf16 output (for kvexp) =============================
__global__ __launch_bounds__(256) void gemm_bt_h(const ushort* __restrict__ A,
                                                 const ushort* __restrict__ BT,
                                                 ushort* __restrict__ C,
                                                 int M, int N, int K) {
    __shared__ ushort As[128 * 32];
    __shared__ ushort Bs[128 * 32];
    const int tid = threadIdx.x;
    const int w = tid >> 6, l = tid & 63;
    const int quad = l >> 4, lane = l & 15;
    const int row0 = blockIdx.y * 128, col0 = blockIdx.x * 128;
    const int wr = (w >> 1) * 64, wc = (w & 1) * 64;
    f32x4 acc[4][4];
#pragma unroll
    for (int i = 0; i < 4; i++)
#pragma unroll
        for (int j = 0; j < 4; j++) acc[i][j] = (f32x4)0.f;

    const int srow = w * 32 + (l >> 2);
    const int c8 = (l & 3) * 8;
    const ushort* pa0 = A + (size_t)(row0 + srow) * K + c8;
    const ushort* pa1 = A + (size_t)(row0 + srow + 16) * K + c8;
    int bn0 = col0 + srow;      if (bn0 > N - 1) bn0 = N - 1;
    int bn1 = col0 + srow + 16; if (bn1 > N - 1) bn1 = N - 1;
    const ushort* pb0 = BT + (size_t)bn0 * K + c8;
    const ushort* pb1 = BT + (size_t)bn1 * K + c8;
    ushort* sa0 = As + srow * 32 + c8;
    ushort* sa1 = sa0 + 16 * 32;
    ushort* sb0 = Bs + srow * 32 + c8;
    ushort* sb1 = sb0 + 16 * 32;

    for (int k0 = 0; k0 < K; k0 += 32) {
        __syncthreads();
        GLL16(pa0 + k0, sa0);
        GLL16(pa1 + k0, sa1);
        GLL16(pb0 + k0, sb0);
        GLL16(pb1 + k0, sb1);
        __syncthreads();
        bf16x8 af[4], bf[4];
#pragma unroll
        for (int mi = 0; mi < 4; mi++)
            af[mi] = *(const bf16x8*)(As + (wr + mi * 16 + lane) * 32 + quad * 8);
#pragma unroll
        for (int ni = 0; ni < 4; ni++)
            bf[ni] = *(const bf16x8*)(Bs + (wc + ni * 16 + lane) * 32 + quad * 8);
#pragma unroll
        for (int mi = 0; mi < 4; mi++)
#pragma unroll
            for (int ni = 0; ni < 4; ni++)
                acc[mi][ni] = __builtin_amdgcn_mfma_f32_16x16x32_bf16(af[mi], bf[ni], acc[mi][ni], 0, 0, 0);
    }
#pragma unroll
    for (int mi = 0; mi < 4; mi++)
#pragma unroll
        for (int ni = 0; ni < 4; ni++)
#pragma unroll
            for (int r = 0; r < 4; r++) {
                int row = row0 + wr + mi * 16 + quad * 4 + r;
                int col = col0 + wc + ni * 16 + lane;
                if (col < N) C[(size_t)row * N + col] = f2b(acc[mi][ni][r]);
            }
}

// ============ generic transpose body =========================================
__device__ __forceinline__ void wtrans_body(const float* W, ushort* WT, int K, int N,
                                            int k0, int n0) {
    __shared__ float t[64][65];
    int rr = threadIdx.x >> 6, cc = threadIdx.x & 63;
#pragma unroll
    for (int p = 0; p < 16; p++) {
        int k = k0 + p * 4 + rr, n = n0 + cc;
        t[p * 4 + rr][cc] = (k < K && n < N) ? W[(size_t)k * N + n] : 0.f;
    }
    __syncthreads();
#pragma unroll
    for (int p = 0; p < 16; p++) {
        int n = n0 + p * 4 + rr, k = k0 + cc;
        if (n < N && k < K) WT[(size_t)n * K + k] = f2b(t[cc][p * 4 + rr]);
    }
}

__global__ __launch_bounds__(256) void wtrans(const float* __restrict__ W, ushort* __restrict__ WT,
                                              int K, int N) {
    wtrans_body(W, WT, K, N, blockIdx.x * 64, blockIdx.y * 64);
}

// merged transposes for the 4 x-side weights (K=2048)
__global__ __launch_bounds__(256) void wtrans_c1(const float* __restrict__ W0, const float* __restrict__ W1,
                                                 const float* __restrict__ W2, const float* __restrict__ W3,
                                                 ushort* __restrict__ WT) {
    int yb = blockIdx.y;
    const float* W; int N; size_t off; int y;
    if (yb < 24)      { W = W0; N = 1536; off = 0;                      y = yb; }
    else if (yb < 33) { W = W1; N = 576;  off = (size_t)1536 * HID;     y = yb - 24; }
    else if (yb < 35) { W = W2; N = 128;  off = (size_t)2112 * HID;     y = yb - 33; }
    else              { W = W3; N = 4;    off = (size_t)2240 * HID;     y = yb - 35; }
    wtrans_body(W, WT + off, HID, N, blockIdx.x * 64, y * 64);
}

// merged transposes for the 2 qr-side weights (K=1536)
__global__ __launch_bounds__(256) void wtrans_c2(const float* __restrict__ W0, const float* __restrict__ W1,
                                                 ushort* __restrict__ WT) {
    int yb = blockIdx.y;
    const float* W; int N; size_t off; int y;
    if (yb < 48) { W = W0; N = 3072; off = 0;                  y = yb; }
    else         { W = W1; N = 512;  off = (size_t)3072 * QL;  y = yb - 48; }
    wtrans_body(W, WT + off, QL, N, blockIdx.x * 64, y * 64);
}

// ============ elementwise f32 -> bf16 (n mult of 1024) =======================
__global__ void cvt_bf16(const float* __restrict__ in, ushort* __restrict__ out) {
    int i = blockIdx.x * 256 + threadIdx.x;
    float4 v = *(const float4*)(in + (size_t)i * 4);
    uint32_t lo = (uint32_t)f2b(v.x) | ((uint32_t)f2b(v.y) << 16);
    uint32_t hi = (uint32_t)f2b(v.z) | ((uint32_t)f2b(v.w) << 16);
    *(uint2*)(out + (size_t)i * 4) = make_uint2(lo, hi);
}

// ============ fused post-C1: rmsnorm(qr), rmsnorm(kv), rope(kpe), LN+rope(ki)+T
__global__ __launch_bounds__(256) void post_c1(const float* __restrict__ C1,
                                               const float* __restrict__ qw,
                                               const float* __restrict__ kvw,
                                               const float* __restrict__ ikg,
                                               const float* __restrict__ ikb,
                                               const float* __restrict__ cosb,
                                               const float* __restrict__ sinb,
                                               ushort* __restrict__ qrb,
                                               ushort* __restrict__ kvnb,
                                               float* __restrict__ kpe,
                                               float* __restrict__ kiT) {
    const int t = blockIdx.x, tid = threadIdx.x;
    const float* row = C1 + (size_t)t * N1;
    __shared__ float red[256];
    __shared__ float kis[128];
    float ss = 0.f;
    for (int i = tid; i < 1536; i += 256) { float v = row[i]; ss += v * v; }
    red[tid] = ss; __syncthreads();
    for (int st = 128; st > 0; st >>= 1) { if (tid < st) red[tid] += red[tid + st]; __syncthreads(); }
    float sq = rsqrtf(red[0] / 1536.f + 1e-6f);
    __syncthreads();
    float s2 = 0.f;
    for (int i = tid; i < 512; i += 256) { float v = row[1536 + i]; s2 += v * v; }
    red[tid] = s2; __syncthreads();
    for (int st = 128; st > 0; st >>= 1) { if (tid < st) red[tid] += red[tid + st]; __syncthreads(); }
    float skv = rsqrtf(red[0] / 512.f + 1e-6f);
    __syncthreads();
    float kv_ = (tid < 128) ? row[2112 + tid] : 0.f;
    red[tid] = kv_; __syncthreads();
    for (int st = 128; st > 0; st >>= 1) { if (tid < st) red[tid] += red[tid + st]; __syncthreads(); }
    float mu = red[0] / 128.f;
    __syncthreads();
    red[tid] = kv_ * kv_; __syncthreads();
    for (int st = 128; st > 0; st >>= 1) { if (tid < st) red[tid] += red[tid + st]; __syncthreads(); }
    float var = red[0] / 128.f - mu * mu;
    for (int i = tid; i < 1536; i += 256) qrb[(size_t)t * QL + i] = f2b(row[i] * sq * qw[i]);
    for (int i = tid; i < 512; i += 256)  kvnb[(size_t)t * KVL + i] = f2b(row[1536 + i] * skv * kvw[i]);
    if (tid < 32) {
        float c = cosb[t * 32 + tid], s = sinb[t * 32 + tid];
        float xr = row[2048 + 2 * tid], xi = row[2048 + 2 * tid + 1];
        kpe[t * 64 + 2 * tid]     = xr * c - xi * s;
        kpe[t * 64 + 2 * tid + 1] = xr * s + xi * c;
    }
    if (tid < 128) kis[tid] = (kv_ - mu) * rsqrtf(var + 1e-6f) * ikg[tid] + ikb[tid];
    __syncthreads();
    if (tid < 128) {
        float outv;
        if (tid < 32) {
            float c = cosb[t * 32 + tid], s = sinb[t * 32 + tid];
            outv = kis[tid] * c - kis[tid + 32] * s;
        } else if (tid < 64) {
            int j = tid - 32;
            float c = cosb[t * 32 + j], s = sinb[t * 32 + j];
            outv = kis[j] * s + kis[tid] * c;
        } else {
            outv = kis[tid];
        }
        kiT[(size_t)tid * S + t] = outv;
    }
}

// ============ fused post-C2: q rope+scale -> qb, qi rope in place ============
__global__ __launch_bounds__(256) void post_c2(float* __restrict__ C2,
                                               const float* __restrict__ cosb,
                                               const float* __restrict__ sinb,
                                               ushort* __restrict__ qb) {
    const int t = blockIdx.x, tid = threadIdx.x;
    __shared__ float cs[32], sn[32];
    if (tid < 32) { cs[tid] = cosb[t * 32 + tid]; sn[tid] = sinb[t * 32 + tid]; }
    __syncthreads();
    const float sc = 0.10412775370051047f;  // 192^-0.5 * log2(e) (exp2-domain softmax)
    const float* src0 = C2 + (size_t)t * N2;
    for (int i = tid; i < NH * 96; i += 256) {
        int h = i / 96, p = i % 96;
        const float* src = src0 + h * 192;
        ushort* dst = qb + ((size_t)h * S + t) * 192;
        if (p < 64) {
            dst[2 * p]     = f2b(src[2 * p] * sc);
            dst[2 * p + 1] = f2b(src[2 * p + 1] * sc);
        } else {
            int j = p - 64;
            float c = cs[j], s = sn[j];
            float xr = src[128 + 2 * j], xi = src[128 + 2 * j + 1];
            dst[128 + 2 * j]     = f2b((xr * c - xi * s) * sc);
            dst[128 + 2 * j + 1] = f2b((xr * s + xi * c) * sc);
        }
    }
    if (tid < 128) {
        int h = tid >> 5, j = tid & 31;
        float* p = C2 + (size_t)t * N2 + 3072 + h * 128;
        float c = cs[j], s = sn[j];
        float x1 = p[j], x2 = p[j + 32];
        p[j] = x1 * c - x2 * s;
        p[j + 32] = x1 * s + x2 * c;
    }
}

// ============ pack kvexp_h + kpe -> kb[NH][S][192], vT[NH][128][S] ===========
__global__ __launch_bounds__(256) void pack_kv(const ushort* __restrict__ kvexp_h,
                                               const float* __restrict__ kpe,
                                               ushort* __restrict__ kb,
                                               ushort* __restrict__ vT) {
    __shared__ ushort t[64][136];
    const int s0 = blockIdx.x * 64, h = blockIdx.y, tid = threadIdx.x;
    const int row = tid >> 2, c = tid & 3;
    const ushort* src = kvexp_h + (size_t)(s0 + row) * 4096 + h * 256;
    ushort* kbr = kb + ((size_t)h * S + s0 + row) * 192;
#pragma unroll
    for (int i = 0; i < 4; i++) {
        int off = c * 32 + i * 8;
        *(uint4*)(kbr + off) = *(const uint4*)(src + off);
        *(uint4*)(&t[row][off]) = *(const uint4*)(src + 128 + off);
    }
    const float* kp = kpe + (size_t)(s0 + row) * 64 + c * 16;
#pragma unroll
    for (int i = 0; i < 16; i++) kbr[128 + c * 16 + i] = f2b(kp[i]);
    __syncthreads();
    const int d = tid >> 1, sh = (tid & 1) * 32;
    ushort* dst = vT + ((size_t)h * 128 + d) * S + s0 + sh;
#pragma unroll
    for (int i = 0; i < 32; i++) dst[i] = t[sh + i][d];
}

// ============ indexer score (fp32, 4 cols/thread, causal region only) ========
__global__ __launch_bounds__(256) void iscore4(const float* __restrict__ qi,
                                               const float* __restrict__ kiT,
                                               const float* __restrict__ iw,
                                               float* __restrict__ iscore) {
    int t = blockIdx.x;
    int s0 = blockIdx.y * 1024;
    if (s0 > t) return;
    int s = s0 + threadIdx.x * 4;
    __shared__ float qs[4 * ID];
    __shared__ float ws4[4];
    for (int i = threadIdx.x; i < 4 * ID; i += 256) qs[i] = qi[(size_t)t * N2 + i];
    if (threadIdx.x < 4) ws4[threadIdx.x] = iw[(size_t)t * N1 + threadIdx.x] * 0.04419417382415922f;
    __syncthreads();
    if (s > t) return;
    float a[4][4];
#pragma unroll
    for (int h = 0; h < 4; h++)
#pragma unroll
        for (int c = 0; c < 4; c++) a[h][c] = 0.f;
    for (int d = 0; d < ID; d++) {
        float4 kv = *(const float4*)(kiT + (size_t)d * S + s);
#pragma unroll
        for (int h = 0; h < 4; h++) {
            float qv = qs[h * ID + d];
            a[h][0] += qv * kv.x; a[h][1] += qv * kv.y;
            a[h][2] += qv * kv.z; a[h][3] += qv * kv.w;
        }
    }
#pragma unroll
    for (int c = 0; c < 4; c++) {
        if (s + c > t) break;
        float sc = fmaxf(a[0][c], 0.f) * ws4[0] + fmaxf(a[1][c], 0.f) * ws4[1] +
                   fmaxf(a[2][c], 0.f) * ws4[2] + fmaxf(a[3][c], 0.f) * ws4[3];
        iscore[(size_t)t * S + s + c] = sc;
    }
}

// ============ exact top-k -> bitmask (registers-resident radix select) =======
__device__ inline unsigned sortable_u32(float f) {
    unsigned u = __float_as_uint(f);
    return (u & 0x80000000u) ? ~u : (u | 0x80000000u);
}

__global__ __launch_bounds__(256) void topk_mask(const float* __restrict__ iscore,
                                                 uint32_t* __restrict__ msk) {
    int t = blockIdx.x, tid = threadIdx.x;
    uint32_t* mrow = msk + (size_t)t * 64;
    if (t < TOPK) {
        if (tid < 64) {
            int full = (t + 1) >> 5;
            uint32_t wv2 = (tid < full) ? 0xFFFFFFFFu : 0u;
            if (tid == full) { int rem = (t + 1) & 31; wv2 = rem ? ((1u << rem) - 1u) : 0u; }
            mrow[tid] = wv2;
        }
        return;
    }
    const float* row = iscore + (size_t)t * S;
    const int n = t + 1;
    const int wv = tid >> 6;
    __shared__ int hist[4][256];
    __shared__ int scan[256];
    __shared__ int bsel, ksel;
    __shared__ uint32_t bytes[256];

    int jb = tid * 8;
    float4 v0 = *(const float4*)(row + jb);
    float4 v1 = *(const float4*)(row + jb + 4);
    uint32_t lsu[8];
    {
        float vvv[8] = {v0.x, v0.y, v0.z, v0.w, v1.x, v1.y, v1.z, v1.w};
#pragma unroll
        for (int i = 0; i < 8; i++)
            lsu[i] = (jb + i < n) ? sortable_u32(vvv[i]) : 0u;
    }
    unsigned prefix = 0, prefmask = 0;
    int k = TOPK;
    for (int pass = 0; pass < 4; pass++) {
        int shift = 24 - pass * 8;
#pragma unroll
        for (int r = 0; r < 4; r++) hist[r][tid] = 0;
        __syncthreads();
#pragma unroll
        for (int i = 0; i < 8; i++) {
            uint32_t u = lsu[i];
            if ((u & prefmask) == prefix) atomicAdd(&hist[wv][(u >> shift) & 255], 1);
        }
        __syncthreads();
        int h = hist[0][tid] + hist[1][tid] + hist[2][tid] + hist[3][tid];
        scan[tid] = h; __syncthreads();
        for (int st = 1; st < 256; st <<= 1) {
            int a = scan[tid];
            int b = (tid + st < 256) ? scan[tid + st] : 0;
            __syncthreads();
            scan[tid] = a + b;
            __syncthreads();
        }
        int snext = (tid < 255) ? scan[tid + 1] : 0;
        if (scan[tid] >= k && snext < k) { bsel = tid; ksel = k - snext; }
        __syncthreads();
        prefix |= ((unsigned)bsel) << shift;
        prefmask |= 0xFFu << shift;
        k = ksel;
        __syncthreads();
    }
    const unsigned u_thr = prefix;
    const int need = k;
    uint32_t gtbits = 0, eqbits = 0;
    int eqcnt = 0;
#pragma unroll
    for (int i = 0; i < 8; i++) {
        uint32_t u = lsu[i];
        if (u > u_thr) gtbits |= 1u << i;
        else if (u == u_thr) { eqbits |= 1u << i; eqcnt++; }
    }
    scan[tid] = eqcnt; __syncthreads();
    for (int st = 1; st < 256; st <<= 1) {
        int a = scan[tid];
        int b = (tid >= st) ? scan[tid - st] : 0;
        __syncthreads();
        scan[tid] = a + b;
        __syncthreads();
    }
    int room = need - (scan[tid] - eqcnt);
    uint32_t keep = 0;
#pragma unroll
    for (int i = 0; i < 8; i++)
        if ((eqbits >> i) & 1u) { if (room > 0) { keep |= 1u << i; room--; } }
    bytes[tid] = gtbits | keep;
    __syncthreads();
    if (tid < 64)
        mrow[tid] = bytes[tid * 4] | (bytes[tid * 4 + 1] << 8) |
                    (bytes[tid * 4 + 2] << 16) | (bytes[tid * 4 + 3] << 24);
}

// ============ split-K flash attention v6 =====================================
// v5 structure with launch_bounds (256,2): v5's (256,3) capped VGPRs at 84 and
// spilled acc+Q frags to scratch (FETCH 171MB/WRITE 293MB — the R7 regression).
// At ~120 VGPRs, 4 waves/SIMD schedulable; LDS 49KB binds at 3 blocks/CU.
__global__ __launch_bounds__(256, 2) void fattn6(const ushort* __restrict__ qb,
                                                 const ushort* __restrict__ kb,
                                                 const ushort* __restrict__ vT,
                                                 const uint32_t* __restrict__ msk,
                                                 float* __restrict__ Opart,
                                                 float* __restrict__ mlbuf) {
    __shared__ ushort Ks[24 * 512];   // 24 KB
    __shared__ ushort Vs[16 * 512];   // 16 KB
    __shared__ ushort Pm[4][16 * 72]; // 9 KB
    const int tid = threadIdx.x;
    const int w = tid >> 6, l = tid & 63, quad = l >> 4, lane = l & 15;
    const int b = blockIdx.x;
    const int r8 = b & 7, j = b >> 3;
    const int h = r8 + 8 * (j & 1);
    const int idx = j >> 1;
    const int pair = idx & 15, part = idx >> 4;
    const int ta = pair, tb = 31 - pair, nA = ta + 1;
    const int vlo = part * 11, vhi = vlo + 11;
    const int qa0 = ta * 64, qb0 = tb * 64;

    bf16x8 qfa[6], qfb[6];
    {
        const ushort* qpa = qb + ((size_t)h * S + qa0 + w * 16 + lane) * 192;
        const ushort* qpb = qb + ((size_t)h * S + qb0 + w * 16 + lane) * 192;
#pragma unroll
        for (int ks = 0; ks < 6; ks++) {
            qfa[ks] = *(const bf16x8*)(qpa + ks * 32 + quad * 8);
            qfb[ks] = *(const bf16x8*)(qpb + ks * 32 + quad * 8);
        }
    }
    f32x4 oa[8], ob[8];
#pragma unroll
    for (int i = 0; i < 8; i++) { oa[i] = (f32x4)0.f; ob[i] = (f32x4)0.f; }
    float ma[4], la[4], mb[4], lb[4];
#pragma unroll
    for (int r = 0; r < 4; r++) { ma[r] = -1e30f; la[r] = 0.f; mb[r] = -1e30f; lb[r] = 0.f; }

    ushort* pw = &Pm[w][0];
    const ushort* kbase = kb + (size_t)h * S * 192;
    const ushort* vbase = vT + (size_t)h * 128 * S;

    for (int kt = 0; kt <= tb; kt++) {
        const int idxB = (kt <= ta) ? 2 * kt : kt + nA;
        const int hasA = (kt <= ta);
        const int idxA = 2 * kt + 1;
        const bool doB = (idxB >= vlo && idxB < vhi);
        const bool doA = hasA && (idxA >= vlo && idxA < vhi);
        if (!(doA || doB)) continue;           // block-uniform
        const int s0 = kt * 64;
        __syncthreads();
        // ---- DMA K: 24 issues (6/wave). issue i: ks=i>>2, kq=i&3; lane: quad,r15
#pragma unroll
        for (int ii = 0; ii < 6; ii++) {
            const int i = w * 6 + ii;
            const int ks = i >> 2, kq = i & 3;
            const ushort* src = kbase + (size_t)(s0 + kq * 16 + lane) * 192 + ks * 32 + quad * 8;
            GLL16(src, Ks + i * 512 + l * 8);
        }
        // ---- DMA V: 16 issues (4/wave). issue i: k2=i>>3, nt=i&7; lane: quad,d15
#pragma unroll
        for (int ii = 0; ii < 4; ii++) {
            const int i = w * 4 + ii;
            const int k2 = i >> 3, nt = i & 7;
            const ushort* src = vbase + (size_t)(nt * 16 + lane) * S + s0 + k2 * 32 + quad * 8;
            GLL16(src, Vs + i * 512 + l * 8);
        }
        __syncthreads();   // drains DMA

#pragma unroll
        for (int pass = 0; pass < 2; pass++) {
            if (pass == 0 && !doA) continue;
            if (pass == 1 && !doB) continue;
            const bf16x8* qf = (pass == 0) ? qfa : qfb;
            f32x4* oacc      = (pass == 0) ? oa : ob;
            float* mm        = (pass == 0) ? ma : mb;
            float* ll        = (pass == 0) ? la : lb;
            const int q0t    = (pass == 0) ? qa0 : qb0;

            // QK^T (scores in log2e domain)
            f32x4 sc[4];
#pragma unroll
            for (int kq = 0; kq < 4; kq++) {
                sc[kq] = (f32x4)0.f;
#pragma unroll
                for (int ks = 0; ks < 6; ks++) {
                    bf16x8 bfr = *(const bf16x8*)(Ks + (ks * 4 + kq) * 512 + quad * 128 + lane * 8);
                    sc[kq] = __builtin_amdgcn_mfma_f32_16x16x32_bf16(qf[ks], bfr, sc[kq], 0, 0, 0);
                }
            }
            // mask words
            uint32_t w0[4], w1[4];
            {
                const int rowbase = q0t + w * 16 + quad * 4;
#pragma unroll
                for (int r = 0; r < 4; r++) {
                    const uint32_t* mp = msk + (size_t)(rowbase + r) * 64 + (s0 >> 5);
                    w0[r] = mp[0]; w1[r] = mp[1];
                }
            }
            float vmax[4] = {-1e30f, -1e30f, -1e30f, -1e30f};
#pragma unroll
            for (int kq = 0; kq < 4; kq++) {
                const int sh = (kq & 1) * 16 + lane;
#pragma unroll
                for (int r = 0; r < 4; r++) {
                    uint32_t word = (kq < 2) ? w0[r] : w1[r];
                    float v = ((word >> sh) & 1u) ? sc[kq][r] : -1e30f;
                    sc[kq][r] = v;
                    vmax[r] = fmaxf(vmax[r], v);
                }
            }
#pragma unroll
            for (int off = 1; off < 16; off <<= 1)
#pragma unroll
                for (int r = 0; r < 4; r++)
                    vmax[r] = fmaxf(vmax[r], __shfl_xor(vmax[r], off, 64));
            float alpha[4], psum[4];
#pragma unroll
            for (int r = 0; r < 4; r++) {
                float mnew = fmaxf(mm[r], vmax[r]);
                alpha[r] = exp2f(mm[r] - mnew);
                mm[r] = mnew;
                psum[r] = 0.f;
            }
#pragma unroll
            for (int kq = 0; kq < 4; kq++)
#pragma unroll
                for (int r = 0; r < 4; r++) {
                    float v = sc[kq][r];
                    float e = (v < -1e29f) ? 0.f : exp2f(v - mm[r]);
                    psum[r] += e;
                    pw[(quad * 4 + r) * 72 + kq * 16 + lane] = f2b(e);
                }
#pragma unroll
            for (int off = 1; off < 16; off <<= 1)
#pragma unroll
                for (int r = 0; r < 4; r++)
                    psum[r] += __shfl_xor(psum[r], off, 64);
#pragma unroll
            for (int r = 0; r < 4; r++) ll[r] = ll[r] * alpha[r] + psum[r];

            bf16x8 pfr[2];
#pragma unroll
            for (int k2 = 0; k2 < 2; k2++)
                pfr[k2] = *(const bf16x8*)(pw + lane * 72 + k2 * 32 + quad * 8);
#pragma unroll
            for (int nt = 0; nt < 8; nt++) {
#pragma unroll
                for (int r = 0; r < 4; r++) oacc[nt][r] *= alpha[r];
#pragma unroll
                for (int k2 = 0; k2 < 2; k2++) {
                    bf16x8 vfr = *(const bf16x8*)(Vs + ((k2 * 8 + nt) * 4 + quad) * 128 + lane * 8);
                    oacc[nt] = __builtin_amdgcn_mfma_f32_16x16x32_bf16(pfr[k2], vfr, oacc[nt], 0, 0, 0);
                }
            }
        }
    }
    // epilogue: f32 partials (unnormalized O + m,l), 3 parts
#pragma unroll
    for (int pass = 0; pass < 2; pass++) {
        const f32x4* oacc = (pass == 0) ? oa : ob;
        const float* mm   = (pass == 0) ? ma : mb;
        const float* ll   = (pass == 0) ? la : lb;
        const int qt      = (pass == 0) ? ta : tb;
        float* Op = Opart + (size_t)((qt * 16 + h) * 3 + part) * (64 * 128);
        float* mlp = mlbuf + (size_t)((qt * 16 + h) * 3 + part) * 128;
#pragma unroll
        for (int nt = 0; nt < 8; nt++)
#pragma unroll
            for (int r = 0; r < 4; r++)
                Op[(w * 16 + quad * 4 + r) * 128 + nt * 16 + lane] = oacc[nt][r];
        if (lane == 0) {
#pragma unroll
            for (int r = 0; r < 4; r++) {
                mlp[(w * 16 + quad * 4 + r) * 2 + 0] = mm[r];
                mlp[(w * 16 + quad * 4 + r) * 2 + 1] = ll[r];
            }
        }
    }
}

// ============ combine 3 split-K partials -> attn_b bf16 ======================
__global__ __launch_bounds__(256) void attn_combine(const float* __restrict__ Opart,
                                                    const float* __restrict__ mlbuf,
                                                    ushort* __restrict__ attn_b) {
    const int qt = blockIdx.x, h = blockIdx.y, tid = threadIdx.x;
    const size_t base = ((size_t)qt * 16 + h) * 3;
    const float* Op0 = Opart + base * 8192;
    const float* Op1 = Op0 + 8192;
    const float* Op2 = Op1 + 8192;
    const float* ml0 = mlbuf + base * 128;
    const float* ml1 = ml0 + 128;
    const float* ml2 = ml1 + 128;
#pragma unroll
    for (int i = 0; i < 32; i++) {
        int id = tid + i * 256;
        int row = id >> 7, d = id & 127;
        float m0 = ml0[row * 2], l0 = ml0[row * 2 + 1];
        float m1 = ml1[row * 2], l1 = ml1[row * 2 + 1];
        float m2 = ml2[row * 2], l2 = ml2[row * 2 + 1];
        float m = fmaxf(fmaxf(m0, m1), m2);
        float e0 = exp2f(m0 - m), e1 = exp2f(m1 - m), e2 = exp2f(m2 - m);
        float linv = 1.f / (l0 * e0 + l1 * e1 + l2 * e2);
        float v = (Op0[id] * e0 + Op1[id] * e1 + Op2[id] * e2) * linv;
        attn_b[(size_t)(qt * 64 + row) * 2048 + h * 128 + d] = f2b(v);
    }
}

// ============ host ===========================================================
extern "C" void kernel_launch(void* const* d_in, const int* in_sizes, int n_in,
                              void* d_out, int out_size, void* d_ws, size_t ws_size,
                              hipStream_t stream) {
    const float* x        = (const float*)d_in[0];
    const float* cosb     = (const float*)d_in[1];
    const float* sinb     = (const float*)d_in[2];
    const float* Wq_a     = (const float*)d_in[4];
    const float* q_norm_w = (const float*)d_in[5];
    const float* Wq_b     = (const float*)d_in[6];
    const float* Wkv_a    = (const float*)d_in[7];
    const float* kv_norm_w= (const float*)d_in[8];
    const float* Wkv_b    = (const float*)d_in[9];
    const float* Wo       = (const float*)d_in[10];
    const float* IWq_b    = (const float*)d_in[11];
    const float* IWk      = (const float*)d_in[12];
    const float* Ik_norm_w= (const float*)d_in[13];
    const float* Ik_norm_b= (const float*)d_in[14];
    const float* IWproj   = (const float*)d_in[15];
    float* out = (float*)d_out;

    char* ws = (char*)d_ws;
    size_t o = 0;
    auto take = [&](size_t b) { char* p = ws + o; o += (b + 255) & ~(size_t)255; return p; };
    ushort* xb     = (ushort*)take((size_t)S * HID * 2);
    ushort* qrb    = (ushort*)take((size_t)S * QL * 2);
    ushort* qb     = (ushort*)take((size_t)NH * S * DQ * 2);
    ushort* kvnb   = (ushort*)take((size_t)S * KVL * 2);
    float*  kpe    = (float*)take((size_t)S * DR * 4);
    ushort* kb     = (ushort*)take((size_t)NH * S * DQ * 2);
    ushort* vT     = (ushort*)take((size_t)NH * DV * S * 2);
    uint32_t* msk  = (uint32_t*)take((size_t)S * 64 * 4);
    float*  mlbuf  = (float*)take((size_t)32 * 16 * 3 * 64 * 2 * 4);
    ushort* WTp    = (ushort*)take((size_t)N2 * QL * 2);            // reused serially
    float*  C1     = (float*)take((size_t)S * N1 * 4);
    char*   big    = take((size_t)32 * 16 * 3 * 8192 * 4 + 1024);   // C2 f32 then Opart
    ushort* kvexp_h= (ushort*)take((size_t)S * 4096 * 2);
    float*  kiT    = (float*)take((size_t)128 * S * 4);
    char*   poolb  = take((size_t)16777216);                        // iscore / attn_b

    float* C2     = (float*)big;              // [S][N2] (qi consumed by iscore)
    float* Opart  = (float*)big;              // [32][16][3][64][128] f32
    float* iscore = (float*)poolb;
    ushort* attn_b = (ushort*)poolb;          // after topk consumed iscore

    // --- x -> bf16
    cvt_bf16<<<(S * HID) / 1024, 256, 0, stream>>>(x, xb);

    // --- concatenated x-GEMM + fused post-processing
    wtrans_c1<<<dim3(32, 36), 256, 0, stream>>>(Wq_a, Wkv_a, IWk, IWproj, WTp);
    gemm_bt<<<dim3(CDIV(N1, 128), S / 128), 256, 0, stream>>>(xb, WTp, C1, S, N1, HID);
    post_c1<<<S, 256, 0, stream>>>(C1, q_norm_w, kv_norm_w, Ik_norm_w, Ik_norm_b,
                                   cosb, sinb, qrb, kvnb, kpe, kiT);

    // --- concatenated qr-GEMM + fused rope
    wtrans_c2<<<dim3(24, 56), 256, 0, stream>>>(Wq_b, IWq_b, WTp);
    gemm_bt<<<dim3(N2 / 128, S / 128), 256, 0, stream>>>(qrb, WTp, C2, S, N2, QL);
    post_c2<<<S, 256, 0, stream>>>(C2, cosb, sinb, qb);

    // --- kv_exp (bf16 out) ; pack kb / vT
    wtrans<<<dim3(8, 64), 256, 0, stream>>>(Wkv_b, WTp, KVL, NH * (DN + DV));
    gemm_bt_h<<<dim3(32, S / 128), 256, 0, stream>>>(kvnb, WTp, kvexp_h, S, NH * (DN + DV), KVL);
    pack_kv<<<dim3(S / 64, NH), 256, 0, stream>>>(kvexp_h, kpe, kb, vT);

    // --- indexer scores + exact top-k -> bitmap
    iscore4<<<dim3(S, S / 1024), 256, 0, stream>>>(C2 + 3072, kiT, C1 + 2240, iscore);
    topk_mask<<<S, 256, 0, stream>>>(iscore, msk);

    // --- split-K masked flash attention (3 parts) + combine
    fattn6<<<768, 256, 0, stream>>>(qb, kb, vT, msk, Opart, mlbuf);
    attn_combine<<<dim3(32, 16), 256, 0, stream>>>(Opart, mlbuf, attn_b);

    // --- out = attn @ Wo
    wtrans<<<dim3(32, 32), 256, 0, stream>>>(Wo, WTp, NH * DV, HID);
    gemm_bt<<<dim3(HID / 128, S / 128), 256, 0, stream>>>(attn_b, WTp, out, S, HID, NH * DV);

    (void)in_sizes; (void)n_in; (void)out_size; (void)ws_size; (void)o;
}